// Round 1
// baseline (109.818 us; speedup 1.0000x reference)
//
#include <hip/hip_runtime.h>
#include <math.h>

#define NN 2048
#define DD 16
#define HH 128
#define EPSF 1e-10f
#define PIO2 1.57079632679489662f

// ---------------- workspace float layout ----------------
// [0] lossExceed  [1] lossShapeLike  [2] lossOverlap  [3] sum_r2  [4] sum_o2
#define SC   0
#define CSD  8                 // colsumDiff[16]
#define CSR  32                // colsum_r[N]
#define CSO  (32 + NN)         // colsum_o[N]
#define SQ   (32 + 2*NN)       // sq[N]
#define CLG  (32 + 3*NN)       // gathered lower [N*16]
#define CHG  (32 + 3*NN + NN*DD) // gathered higher [N*16]
#define ZERO_BYTES ((32 + 2*NN) * 4)   // zero scalars + colsumDiff + colsum_r + colsum_o

__device__ __forceinline__ float waveReduce(float v) {
    #pragma unroll
    for (int o = 32; o > 0; o >>= 1) v += __shfl_down(v, o, 64);
    return v;
}

// ---------------- kernel A: gather + elementwise terms + sq ----------------
__global__ __launch_bounds__(256) void k_setup(
    const int* __restrict__ idx, const float* __restrict__ omega,
    const float* __restrict__ chL, const float* __restrict__ chH,
    const float* __restrict__ pL, const float* __restrict__ pH,
    const float* __restrict__ pR, const float* __restrict__ lr,
    float* __restrict__ ws)
{
    int t = threadIdx.x;
    int i = blockIdx.x * 256 + t;           // grid = 8 blocks -> i < 2048 always
    int id = idx[i];

    float cl[16], ch[16];
    const float4* clp = (const float4*)(chL + id * DD);
    const float4* chp = (const float4*)(chH + id * DD);
    #pragma unroll
    for (int q = 0; q < 4; q++) {
        float4 a = clp[q];
        cl[4*q+0] = a.x; cl[4*q+1] = a.y; cl[4*q+2] = a.z; cl[4*q+3] = a.w;
        float4 b = chp[q];
        ch[4*q+0] = b.x; ch[4*q+1] = b.y; ch[4*q+2] = b.z; ch[4*q+3] = b.w;
    }
    // store gathered boxes for pairwise pass
    float4* clg4 = (float4*)(ws + CLG + i * DD);
    float4* chg4 = (float4*)(ws + CHG + i * DD);
    #pragma unroll
    for (int q = 0; q < 4; q++) { clg4[q] = clp[q]; chg4[q] = chp[q]; }

    float denom = lr[id];
    float ex = 0.f, sh = 0.f;
    float dsum[16];
    #pragma unroll
    for (int d = 0; d < 16; d++) {
        float c0 = cl[d], c1 = ch[d];
        float l = pL[d], h = pH[d], r = pR[d];
        ex += fmaxf(l - c0, 0.f) + fmaxf(c1 - h, 0.f)
            + fmaxf(l - c1, 0.f) + fmaxf(c0 - h, 0.f);
        float diff = c1 - c0;
        dsum[d] = diff;
        float numer = fmaxf(diff / r, EPSF);
        float sdiv = fminf(fmaxf(numer / denom, 0.01f), 1.99f);
        sh += fabsf(tanf((sdiv - 1.0f) * PIO2));
    }

    // sq_i = sum omega^2
    const float4* op = (const float4*)(omega + i * HH);
    float s = 0.f;
    #pragma unroll
    for (int q = 0; q < HH/4; q++) {
        float4 v = op[q];
        s = fmaf(v.x, v.x, fmaf(v.y, v.y, fmaf(v.z, v.z, fmaf(v.w, v.w, s))));
    }
    ws[SQ + i] = s;

    // block reductions
    __shared__ float scol[16];
    __shared__ float pex[4], psh[4];
    if (t < 16) scol[t] = 0.f;
    __syncthreads();
    #pragma unroll
    for (int d = 0; d < 16; d++) atomicAdd(&scol[d], dsum[d]);
    float exw = waveReduce(ex), shw = waveReduce(sh);
    if ((t & 63) == 0) { pex[t >> 6] = exw; psh[t >> 6] = shw; }
    __syncthreads();
    if (t < 16) atomicAdd(&ws[CSD + t], scol[t]);
    if (t == 0) {
        atomicAdd(&ws[SC + 0], pex[0] + pex[1] + pex[2] + pex[3]);
        atomicAdd(&ws[SC + 1], psh[0] + psh[1] + psh[2] + psh[3]);
    }
}

// ---------------- kernel B: box pairwise (overlap + L1 dist stats) ----------------
// grid (8, 32): blockIdx.x = j-tile of 256, blockIdx.y = i-chunk of 64
__global__ __launch_bounds__(256) void k_boxpair(float* __restrict__ ws)
{
    __shared__ float sCl[64 * DD];
    __shared__ float sCh[64 * DD];
    int t = threadIdx.x;
    int j = blockIdx.x * 256 + t;
    int ic = blockIdx.y;

    const float* clg = ws + CLG;
    const float* chg = ws + CHG;

    float clj[16], chj[16];
    const float4* cj4 = (const float4*)(clg + j * DD);
    const float4* hj4 = (const float4*)(chg + j * DD);
    #pragma unroll
    for (int q = 0; q < 4; q++) {
        float4 a = cj4[q];
        clj[4*q+0] = a.x; clj[4*q+1] = a.y; clj[4*q+2] = a.z; clj[4*q+3] = a.w;
        float4 b = hj4[q];
        chj[4*q+0] = b.x; chj[4*q+1] = b.y; chj[4*q+2] = b.z; chj[4*q+3] = b.w;
    }
    // stage i-chunk: 64 rows * 16 floats = 256 float4, one per thread
    ((float4*)sCl)[t] = ((const float4*)(clg + ic * 64 * DD))[t];
    ((float4*)sCh)[t] = ((const float4*)(chg + ic * 64 * DD))[t];
    __syncthreads();

    float colAcc = 0.f, ovAcc = 0.f, r2Acc = 0.f;
    for (int ii = 0; ii < 64; ii++) {
        const float* ci = sCl + ii * DD;
        const float* hi = sCh + ii * DD;
        float r = 0.f, ov = 0.f;
        #pragma unroll
        for (int d = 0; d < 16; d++) {
            float a = clj[d] - ci[d];
            r += fabsf(a);
            float mh = fminf(chj[d], hi[d]);
            float ml = fmaxf(clj[d], ci[d]);
            ov += fmaxf(mh - ml, 0.f);
        }
        if (ic * 64 + ii != j) ovAcc += ov;   // off-diagonal mask
        colAcc += r;
        r2Acc = fmaf(r, r, r2Acc);
    }
    atomicAdd(&ws[CSR + j], colAcc);
    float ovW = waveReduce(ovAcc), r2W = waveReduce(r2Acc);
    __shared__ float p1[4], p2[4];
    if ((t & 63) == 0) { p1[t >> 6] = ovW; p2[t >> 6] = r2W; }
    __syncthreads();
    if (t == 0) {
        atomicAdd(&ws[SC + 2], p1[0] + p1[1] + p1[2] + p1[3]);
        atomicAdd(&ws[SC + 3], p2[0] + p2[1] + p2[2] + p2[3]);
    }
}

// ---------------- kernel C: omega Gram stats (no N^2 materialization) ----------------
// 64x64 tile per block, 4x4 microtile per thread, K=128 in steps of 32.
#define BT 64
#define BK 32
#define LSTR 36   // 36 floats = 144B, 16B-aligned rows, bank-stride 4
__global__ __launch_bounds__(256) void k_omega(
    const float* __restrict__ omega, float* __restrict__ ws)
{
    __shared__ float sA[BT * LSTR];
    __shared__ float sB[BT * LSTR];
    __shared__ float cols[64];
    __shared__ float osum[4];

    int t = threadIdx.x;
    int ti = t & 15, tj = t >> 4;
    int i0 = blockIdx.x * BT, j0 = blockIdx.y * BT;

    float acc[4][4];
    #pragma unroll
    for (int u = 0; u < 4; u++)
        #pragma unroll
        for (int v = 0; v < 4; v++) acc[u][v] = 0.f;

    int rr = t >> 2, cc = t & 3;   // row 0..63, chunk 0..3 (of 8 float4 per row)
    for (int k0 = 0; k0 < HH; k0 += BK) {
        const float4* ga = (const float4*)(omega + (i0 + rr) * HH + k0);
        float4 va0 = ga[cc], va1 = ga[cc + 4];
        const float4* gb = (const float4*)(omega + (j0 + rr) * HH + k0);
        float4 vb0 = gb[cc], vb1 = gb[cc + 4];
        __syncthreads();
        *(float4*)&sA[rr * LSTR + cc * 4]       = va0;
        *(float4*)&sA[rr * LSTR + (cc + 4) * 4] = va1;
        *(float4*)&sB[rr * LSTR + cc * 4]       = vb0;
        *(float4*)&sB[rr * LSTR + (cc + 4) * 4] = vb1;
        __syncthreads();
        #pragma unroll
        for (int k = 0; k < BK; k += 4) {
            float4 a[4], b[4];
            #pragma unroll
            for (int u = 0; u < 4; u++)
                a[u] = *(const float4*)&sA[(ti + 16*u) * LSTR + k];
            #pragma unroll
            for (int v = 0; v < 4; v++)
                b[v] = *(const float4*)&sB[(tj + 16*v) * LSTR + k];
            #pragma unroll
            for (int u = 0; u < 4; u++)
                #pragma unroll
                for (int v = 0; v < 4; v++) {
                    acc[u][v] = fmaf(a[u].x, b[v].x,
                                fmaf(a[u].y, b[v].y,
                                fmaf(a[u].z, b[v].z,
                                fmaf(a[u].w, b[v].w, acc[u][v]))));
                }
        }
    }

    // epilogue: o = max(sq_i + sq_j - 2*dot, EPS); accumulate sum o^2 and colsum_o[j]
    float sq_i[4], sq_j[4];
    #pragma unroll
    for (int u = 0; u < 4; u++) sq_i[u] = ws[SQ + i0 + ti + 16*u];
    #pragma unroll
    for (int v = 0; v < 4; v++) sq_j[v] = ws[SQ + j0 + tj + 16*v];

    float o2 = 0.f;
    float colv[4] = {0.f, 0.f, 0.f, 0.f};
    #pragma unroll
    for (int u = 0; u < 4; u++)
        #pragma unroll
        for (int v = 0; v < 4; v++) {
            float o = fmaxf(sq_i[u] + sq_j[v] - 2.0f * acc[u][v], EPSF);
            o2 = fmaf(o, o, o2);
            colv[v] += o;
        }

    if (t < 64) cols[t] = 0.f;
    __syncthreads();
    #pragma unroll
    for (int v = 0; v < 4; v++) atomicAdd(&cols[tj + 16*v], colv[v]);
    float o2w = waveReduce(o2);
    if ((t & 63) == 0) osum[t >> 6] = o2w;
    __syncthreads();
    if (t < 64) atomicAdd(&ws[CSO + j0 + t], cols[t]);
    if (t == 0) atomicAdd(&ws[SC + 4], osum[0] + osum[1] + osum[2] + osum[3]);
}

// ---------------- kernel D: finalize ----------------
__global__ __launch_bounds__(256) void k_final(
    const float* __restrict__ pR, float* __restrict__ ws, float* __restrict__ out)
{
    int t = threadIdx.x;
    float sum_r2 = ws[SC + 3], sum_o2 = ws[SC + 4];
    float nr = fmaxf(sqrtf(sum_r2), EPSF);
    float no = fmaxf(sqrtf(sum_o2), EPSF);

    float s_dn2 = 0.f, s_cross = 0.f;
    for (int j = t; j < NN; j += 256) {
        float dn = ws[CSR + j] / nr;
        s_dn2 = fmaf(dn, dn, s_dn2);
        s_cross = fmaf(dn, ws[CSO + j], s_cross);
    }
    __shared__ float r1[4], r2[4];
    float a = waveReduce(s_dn2), b = waveReduce(s_cross);
    if ((t & 63) == 0) { r1[t >> 6] = a; r2[t >> 6] = b; }
    __syncthreads();
    if (t == 0) {
        float dn2 = r1[0] + r1[1] + r1[2] + r1[3];
        float cross = r2[0] + r2[1] + r2[2] + r2[3];
        float ld2 = sum_o2 / (no * no) - (2.0f / no) * cross + (float)NN * dn2;
        float lossDistance = sqrtf(fmaxf(ld2, 0.f));
        float lossPositive = 0.f;
        #pragma unroll
        for (int d = 0; d < 16; d++)
            lossPositive += fmaxf(pR[d] - ws[CSD + d], 0.f);
        out[0] = lossDistance + ws[SC + 0] + ws[SC + 1] + ws[SC + 2] + lossPositive;
    }
}

extern "C" void kernel_launch(void* const* d_in, const int* in_sizes, int n_in,
                              void* d_out, int out_size, void* d_ws, size_t ws_size,
                              hipStream_t stream) {
    const int*   idx   = (const int*)d_in[0];
    const float* omega = (const float*)d_in[1];
    // d_in[2] = epoch (unused)
    const float* chL   = (const float*)d_in[3];
    const float* chH   = (const float*)d_in[4];
    const float* pL    = (const float*)d_in[5];
    const float* pH    = (const float*)d_in[6];
    const float* pR    = (const float*)d_in[7];
    const float* lr    = (const float*)d_in[8];
    float* ws  = (float*)d_ws;
    float* out = (float*)d_out;

    hipMemsetAsync(ws, 0, ZERO_BYTES, stream);
    k_setup<<<dim3(NN / 256), 256, 0, stream>>>(idx, omega, chL, chH, pL, pH, pR, lr, ws);
    k_boxpair<<<dim3(8, 32), 256, 0, stream>>>(ws);
    k_omega<<<dim3(NN / BT, NN / BT), 256, 0, stream>>>(omega, ws);
    k_final<<<1, 256, 0, stream>>>(pR, ws, out);
}

// Round 2
// 66.777 us; speedup vs baseline: 1.6445x; 1.6445x over previous
//
#include <hip/hip_runtime.h>
#include <math.h>

#define NN 2048
#define DD 16
#define HH 128
#define EPSF 1e-10f
#define PIO2 1.57079632679489662f

// ---------------- workspace float layout ----------------
// [0] lossExceed  [1] lossShapeLike  [2] lossOverlap  [3] sum_r2  [4] sum_o2
#define SC   0
#define CSD  8                 // colsumDiff[16]
#define CSR  32                // colsum_r[N]
#define CSO  (32 + NN)         // colsum_o[N]
#define SQ   (32 + 2*NN)       // sq[N]
#define CLG  (32 + 3*NN)       // gathered lower [N*16]
#define CHG  (32 + 3*NN + NN*DD) // gathered higher [N*16]
#define ZERO_BYTES ((32 + 2*NN) * 4)   // zero scalars + colsumDiff + colsum_r + colsum_o

__device__ __forceinline__ float waveReduce(float v) {
    #pragma unroll
    for (int o = 32; o > 0; o >>= 1) v += __shfl_down(v, o, 64);
    return v;
}

// ---------------- kernel A: gather + elementwise terms + sq ----------------
// one (row, dim) pair per thread: 2048*16 = 32768 threads = 128 blocks
__global__ __launch_bounds__(256) void k_setup(
    const int* __restrict__ idx, const float* __restrict__ omega,
    const float* __restrict__ chL, const float* __restrict__ chH,
    const float* __restrict__ pL, const float* __restrict__ pH,
    const float* __restrict__ pR, const float* __restrict__ lr,
    float* __restrict__ ws)
{
    int t = threadIdx.x;
    int g = blockIdx.x * 256 + t;
    int i = g >> 4;          // row 0..2047
    int d = g & 15;          // dim 0..15
    int id = idx[i];         // 16 lanes share the row -> broadcast

    float c0 = chL[id * DD + d];
    float c1 = chH[id * DD + d];
    ws[CLG + i * DD + d] = c0;   // contiguous per wave
    ws[CHG + i * DD + d] = c1;

    float l = pL[d], h = pH[d], r = pR[d];
    float ex = fmaxf(l - c0, 0.f) + fmaxf(c1 - h, 0.f)
             + fmaxf(l - c1, 0.f) + fmaxf(c0 - h, 0.f);
    float diff = c1 - c0;
    float denom = lr[id];
    float numer = fmaxf(diff / r, EPSF);
    float sdiv = fminf(fmaxf(numer / denom, 0.01f), 1.99f);
    float sh = fabsf(tanf((sdiv - 1.0f) * PIO2));

    // sq_i: lane d covers omega[i*128 + d*8 .. +8), reduce over the 16-lane group
    const float4* op = (const float4*)(omega + i * HH + d * 8);
    float4 v0 = op[0], v1 = op[1];
    float s = v0.x*v0.x + v0.y*v0.y + v0.z*v0.z + v0.w*v0.w
            + v1.x*v1.x + v1.y*v1.y + v1.z*v1.z + v1.w*v1.w;
    s += __shfl_xor(s, 1, 64);
    s += __shfl_xor(s, 2, 64);
    s += __shfl_xor(s, 4, 64);
    s += __shfl_xor(s, 8, 64);
    if (d == 0) ws[SQ + i] = s;

    // colsumDiff: sum diff over the 4 rows within this wave (lanes x^16, x^32)
    float dsw = diff;
    dsw += __shfl_xor(dsw, 16, 64);
    dsw += __shfl_xor(dsw, 32, 64);

    __shared__ float scol[16];
    __shared__ float pex[4], psh[4];
    if (t < 16) scol[t] = 0.f;
    __syncthreads();
    if ((t & 63) < 16) atomicAdd(&scol[t & 15], dsw);
    float exw = waveReduce(ex), shw = waveReduce(sh);
    if ((t & 63) == 0) { pex[t >> 6] = exw; psh[t >> 6] = shw; }
    __syncthreads();
    if (t < 16) atomicAdd(&ws[CSD + t], scol[t]);
    if (t == 0) {
        atomicAdd(&ws[SC + 0], pex[0] + pex[1] + pex[2] + pex[3]);
        atomicAdd(&ws[SC + 1], psh[0] + psh[1] + psh[2] + psh[3]);
    }
}

// ---------------- fused pairwise kernel ----------------
// blocks [0, 256): box pairwise (overlap + L1 dist stats)
// blocks [256, 1280): omega Gram stats, 64x64 tile
#define BT 64
#define BK 32
#define LSTR 36   // 36 floats = 144B rows: 16B-aligned, bank-stride 4
#define NBOX 256

__global__ __launch_bounds__(256) void k_pair(
    const float* __restrict__ omega, float* __restrict__ ws)
{
    __shared__ float smem[2 * BT * LSTR + 72];
    int t = threadIdx.x;

    if (blockIdx.x < NBOX) {
        // ---- box pairwise ----
        float* sCl = smem;            // 1024 floats
        float* sCh = smem + 1024;     // 1024 floats
        float* p1  = smem + 2048;
        float* p2  = smem + 2052;
        int b = blockIdx.x;
        int j = (b & 7) * 256 + t;
        int ic = b >> 3;

        const float* clg = ws + CLG;
        const float* chg = ws + CHG;

        float clj[16], chj[16];
        const float4* cj4 = (const float4*)(clg + j * DD);
        const float4* hj4 = (const float4*)(chg + j * DD);
        #pragma unroll
        for (int q = 0; q < 4; q++) {
            float4 a = cj4[q];
            clj[4*q+0] = a.x; clj[4*q+1] = a.y; clj[4*q+2] = a.z; clj[4*q+3] = a.w;
            float4 bb = hj4[q];
            chj[4*q+0] = bb.x; chj[4*q+1] = bb.y; chj[4*q+2] = bb.z; chj[4*q+3] = bb.w;
        }
        ((float4*)sCl)[t] = ((const float4*)(clg + ic * 64 * DD))[t];
        ((float4*)sCh)[t] = ((const float4*)(chg + ic * 64 * DD))[t];
        __syncthreads();

        float colAcc = 0.f, ovAcc = 0.f, r2Acc = 0.f;
        for (int ii = 0; ii < 64; ii++) {
            const float* ci = sCl + ii * DD;
            const float* hi = sCh + ii * DD;
            float r = 0.f, ov = 0.f;
            #pragma unroll
            for (int d = 0; d < 16; d++) {
                float a = clj[d] - ci[d];
                r += fabsf(a);
                float mh = fminf(chj[d], hi[d]);
                float ml = fmaxf(clj[d], ci[d]);
                ov += fmaxf(mh - ml, 0.f);
            }
            if (ic * 64 + ii != j) ovAcc += ov;
            colAcc += r;
            r2Acc = fmaf(r, r, r2Acc);
        }
        atomicAdd(&ws[CSR + j], colAcc);
        float ovW = waveReduce(ovAcc), r2W = waveReduce(r2Acc);
        if ((t & 63) == 0) { p1[t >> 6] = ovW; p2[t >> 6] = r2W; }
        __syncthreads();
        if (t == 0) {
            atomicAdd(&ws[SC + 2], p1[0] + p1[1] + p1[2] + p1[3]);
            atomicAdd(&ws[SC + 3], p2[0] + p2[1] + p2[2] + p2[3]);
        }
    } else {
        // ---- omega Gram tile ----
        float* sA = smem;
        float* sB = smem + BT * LSTR;
        float* cols = smem + 2 * BT * LSTR;   // 64
        float* osum = cols + 64;              // 4
        int b = blockIdx.x - NBOX;
        int ti = t & 15, tj = t >> 4;
        int i0 = (b >> 5) * BT, j0 = (b & 31) * BT;

        float acc[4][4];
        #pragma unroll
        for (int u = 0; u < 4; u++)
            #pragma unroll
            for (int v = 0; v < 4; v++) acc[u][v] = 0.f;

        int rr = t >> 2, cc = t & 3;
        for (int k0 = 0; k0 < HH; k0 += BK) {
            const float4* ga = (const float4*)(omega + (i0 + rr) * HH + k0);
            float4 va0 = ga[cc], va1 = ga[cc + 4];
            const float4* gb = (const float4*)(omega + (j0 + rr) * HH + k0);
            float4 vb0 = gb[cc], vb1 = gb[cc + 4];
            __syncthreads();
            *(float4*)&sA[rr * LSTR + cc * 4]       = va0;
            *(float4*)&sA[rr * LSTR + (cc + 4) * 4] = va1;
            *(float4*)&sB[rr * LSTR + cc * 4]       = vb0;
            *(float4*)&sB[rr * LSTR + (cc + 4) * 4] = vb1;
            __syncthreads();
            #pragma unroll
            for (int k = 0; k < BK; k += 4) {
                float4 a[4], bb[4];
                #pragma unroll
                for (int u = 0; u < 4; u++)
                    a[u] = *(const float4*)&sA[(ti + 16*u) * LSTR + k];
                #pragma unroll
                for (int v = 0; v < 4; v++)
                    bb[v] = *(const float4*)&sB[(tj + 16*v) * LSTR + k];
                #pragma unroll
                for (int u = 0; u < 4; u++)
                    #pragma unroll
                    for (int v = 0; v < 4; v++) {
                        acc[u][v] = fmaf(a[u].x, bb[v].x,
                                    fmaf(a[u].y, bb[v].y,
                                    fmaf(a[u].z, bb[v].z,
                                    fmaf(a[u].w, bb[v].w, acc[u][v]))));
                    }
            }
        }

        float sq_i[4], sq_j[4];
        #pragma unroll
        for (int u = 0; u < 4; u++) sq_i[u] = ws[SQ + i0 + ti + 16*u];
        #pragma unroll
        for (int v = 0; v < 4; v++) sq_j[v] = ws[SQ + j0 + tj + 16*v];

        float o2 = 0.f;
        float colv[4] = {0.f, 0.f, 0.f, 0.f};
        #pragma unroll
        for (int u = 0; u < 4; u++)
            #pragma unroll
            for (int v = 0; v < 4; v++) {
                float o = fmaxf(sq_i[u] + sq_j[v] - 2.0f * acc[u][v], EPSF);
                o2 = fmaf(o, o, o2);
                colv[v] += o;
            }

        if (t < 64) cols[t] = 0.f;
        __syncthreads();
        #pragma unroll
        for (int v = 0; v < 4; v++) atomicAdd(&cols[tj + 16*v], colv[v]);
        float o2w = waveReduce(o2);
        if ((t & 63) == 0) osum[t >> 6] = o2w;
        __syncthreads();
        if (t < 64) atomicAdd(&ws[CSO + j0 + t], cols[t]);
        if (t == 0) atomicAdd(&ws[SC + 4], osum[0] + osum[1] + osum[2] + osum[3]);
    }
}

// ---------------- kernel D: finalize ----------------
__global__ __launch_bounds__(256) void k_final(
    const float* __restrict__ pR, float* __restrict__ ws, float* __restrict__ out)
{
    int t = threadIdx.x;
    float sum_r2 = ws[SC + 3], sum_o2 = ws[SC + 4];
    float nr = fmaxf(sqrtf(sum_r2), EPSF);
    float no = fmaxf(sqrtf(sum_o2), EPSF);

    float s_dn2 = 0.f, s_cross = 0.f;
    for (int j = t; j < NN; j += 256) {
        float dn = ws[CSR + j] / nr;
        s_dn2 = fmaf(dn, dn, s_dn2);
        s_cross = fmaf(dn, ws[CSO + j], s_cross);
    }
    __shared__ float r1[4], r2[4];
    float a = waveReduce(s_dn2), b = waveReduce(s_cross);
    if ((t & 63) == 0) { r1[t >> 6] = a; r2[t >> 6] = b; }
    __syncthreads();
    if (t == 0) {
        float dn2 = r1[0] + r1[1] + r1[2] + r1[3];
        float cross = r2[0] + r2[1] + r2[2] + r2[3];
        float ld2 = sum_o2 / (no * no) - (2.0f / no) * cross + (float)NN * dn2;
        float lossDistance = sqrtf(fmaxf(ld2, 0.f));
        float lossPositive = 0.f;
        #pragma unroll
        for (int d = 0; d < 16; d++)
            lossPositive += fmaxf(pR[d] - ws[CSD + d], 0.f);
        out[0] = lossDistance + ws[SC + 0] + ws[SC + 1] + ws[SC + 2] + lossPositive;
    }
}

extern "C" void kernel_launch(void* const* d_in, const int* in_sizes, int n_in,
                              void* d_out, int out_size, void* d_ws, size_t ws_size,
                              hipStream_t stream) {
    const int*   idx   = (const int*)d_in[0];
    const float* omega = (const float*)d_in[1];
    // d_in[2] = epoch (unused)
    const float* chL   = (const float*)d_in[3];
    const float* chH   = (const float*)d_in[4];
    const float* pL    = (const float*)d_in[5];
    const float* pH    = (const float*)d_in[6];
    const float* pR    = (const float*)d_in[7];
    const float* lr    = (const float*)d_in[8];
    float* ws  = (float*)d_ws;
    float* out = (float*)d_out;

    hipMemsetAsync(ws, 0, ZERO_BYTES, stream);
    k_setup<<<dim3(NN * DD / 256), 256, 0, stream>>>(idx, omega, chL, chH, pL, pH, pR, lr, ws);
    k_pair<<<dim3(NBOX + (NN/BT)*(NN/BT)), 256, 0, stream>>>(omega, ws);
    k_final<<<1, 256, 0, stream>>>(pR, ws, out);
}

// Round 3
// 61.449 us; speedup vs baseline: 1.7871x; 1.0867x over previous
//
#include <hip/hip_runtime.h>
#include <math.h>

#define NN 2048
#define DD 16
#define HH 128
#define EPSF 1e-10f
#define PIO2 1.57079632679489662f

// ---------------- workspace float layout ----------------
#define SC    0      // 8 scalars: [2]=lossOverlap, [3]=sum_r2, [4]=sum_o2
#define PEX   8      // 128 per-block partial lossExceed
#define PSH   136    // 128 per-block partial lossShapeLike
#define PCSD  264    // 128*16 per-block partial colsumDiff
#define CSR   2312   // colsum_r[2048]
#define CSO   4360   // colsum_o[2048]
#define SQ    6408   // sq[2048]
#define CLG   8456   // gathered lower [N*16]
#define CHG   (CLG + NN*DD)

typedef __attribute__((ext_vector_type(8)))  short  bf16x8;
typedef __attribute__((ext_vector_type(16))) float  f32x16;

__device__ __forceinline__ float waveReduce(float v) {
    #pragma unroll
    for (int o = 32; o > 0; o >>= 1) v += __shfl_down(v, o, 64);
    return v;
}

__device__ __forceinline__ unsigned int bf16rne(float x) {
    unsigned int u = __float_as_uint(x);
    u += 0x7fff + ((u >> 16) & 1);
    return u >> 16;
}
__device__ __forceinline__ unsigned int pkbf(float a, float b) {
    return bf16rne(a) | (bf16rne(b) << 16);
}

// ---------------- kernel A: gather + elementwise + sq + zeroing ----------------
// one (row, dim) per thread: 128 blocks x 256
__global__ __launch_bounds__(256) void k_setup(
    const int* __restrict__ idx, const float* __restrict__ omega,
    const float* __restrict__ chL, const float* __restrict__ chH,
    const float* __restrict__ pL, const float* __restrict__ pH,
    const float* __restrict__ pR, const float* __restrict__ lr,
    float* __restrict__ ws)
{
    int t = threadIdx.x, b = blockIdx.x;
    int g = b * 256 + t;
    int i = g >> 4, d = g & 15;
    int id = idx[i];

    float c0 = chL[id * DD + d];
    float c1 = chH[id * DD + d];
    ws[CLG + i * DD + d] = c0;
    ws[CHG + i * DD + d] = c1;

    // zero accumulators for k_pair (stream-ordered before it)
    if (t < 16) { ws[CSR + b * 16 + t] = 0.f; ws[CSO + b * 16 + t] = 0.f; }
    if (b == 0 && t >= 16 && t < 24) ws[SC + (t - 16)] = 0.f;

    float l = pL[d], h = pH[d], r = pR[d];
    float ex = fmaxf(l - c0, 0.f) + fmaxf(c1 - h, 0.f)
             + fmaxf(l - c1, 0.f) + fmaxf(c0 - h, 0.f);
    float diff = c1 - c0;
    float denom = lr[id];
    float numer = fmaxf(diff / r, EPSF);
    float sdiv = fminf(fmaxf(numer / denom, 0.01f), 1.99f);
    float sh = fabsf(tanf((sdiv - 1.0f) * PIO2));

    // sq_i: lane d covers omega[i*128 + d*8 .. +8)
    const float4* op = (const float4*)(omega + i * HH + d * 8);
    float4 v0 = op[0], v1 = op[1];
    float s = v0.x*v0.x + v0.y*v0.y + v0.z*v0.z + v0.w*v0.w
            + v1.x*v1.x + v1.y*v1.y + v1.z*v1.z + v1.w*v1.w;
    s += __shfl_xor(s, 1, 64);
    s += __shfl_xor(s, 2, 64);
    s += __shfl_xor(s, 4, 64);
    s += __shfl_xor(s, 8, 64);
    if (d == 0) ws[SQ + i] = s;

    float dsw = diff;
    dsw += __shfl_xor(dsw, 16, 64);
    dsw += __shfl_xor(dsw, 32, 64);

    __shared__ float scol[16], pex[4], psh[4];
    if (t < 16) scol[t] = 0.f;
    __syncthreads();
    if ((t & 63) < 16) atomicAdd(&scol[t & 15], dsw);
    float exw = waveReduce(ex), shw = waveReduce(sh);
    if ((t & 63) == 0) { pex[t >> 6] = exw; psh[t >> 6] = shw; }
    __syncthreads();
    if (t < 16) ws[PCSD + b * 16 + t] = scol[t];
    if (t == 0) {
        ws[PEX + b] = pex[0] + pex[1] + pex[2] + pex[3];
        ws[PSH + b] = psh[0] + psh[1] + psh[2] + psh[3];
    }
}

// ---------------- fused pairwise kernel ----------------
// blocks [0,1024): omega Gram via bf16 MFMA, 64x64 tile
// blocks [1024,2048): box pairwise, 16-row i-chunk x 256-j tile
__global__ __launch_bounds__(256) void k_pair(
    const float* __restrict__ omega, float* __restrict__ ws)
{
    __shared__ __align__(16) char smem[33568];
    int t = threadIdx.x;
    int b = blockIdx.x;

    if (b < 1024) {
        // ---- Gram tile (MFMA) ----
        float* sqA  = (float*)(smem + 32768);
        float* sqB  = (float*)(smem + 33024);
        float* cols = (float*)(smem + 33280);
        float* osum = (float*)(smem + 33536);
        int i0 = (b >> 5) * 64, j0 = (b & 31) * 64;

        // stage A/B tiles: f32 -> bf16, XOR-swizzled 16B chunks
        int r = t >> 2, q = t & 3;
        const float4* gA = (const float4*)(omega + (i0 + r) * HH) + q * 8;
        const float4* gB = (const float4*)(omega + (j0 + r) * HH) + q * 8;
        #pragma unroll
        for (int n = 0; n < 4; n++) {
            float4 a0 = gA[2*n], a1 = gA[2*n+1];
            float4 b0 = gB[2*n], b1 = gB[2*n+1];
            int c = ((q * 4 + n) ^ (r & 7)) * 16;
            *(uint4*)(smem + r * 256 + c) =
                make_uint4(pkbf(a0.x,a0.y), pkbf(a0.z,a0.w), pkbf(a1.x,a1.y), pkbf(a1.z,a1.w));
            *(uint4*)(smem + 16384 + r * 256 + c) =
                make_uint4(pkbf(b0.x,b0.y), pkbf(b0.z,b0.w), pkbf(b1.x,b1.y), pkbf(b1.z,b1.w));
        }
        if (t < 64) sqA[t] = ws[SQ + i0 + t];
        else if (t < 128) sqB[t - 64] = ws[SQ + j0 + (t - 64)];
        else if (t < 192) cols[t - 128] = 0.f;
        __syncthreads();

        int w = t >> 6, l = t & 63;
        int rh = w >> 1, qc = w & 1, kh = l >> 5;
        int rowA = rh * 32 + (l & 31);
        int rowB = qc * 32 + (l & 31);
        f32x16 acc;
        #pragma unroll
        for (int m = 0; m < 16; m++) acc[m] = 0.f;
        #pragma unroll
        for (int s = 0; s < 8; s++) {
            int ca = ((2*s + kh) ^ (rowA & 7)) * 16;
            int cb = ((2*s + kh) ^ (rowB & 7)) * 16;
            bf16x8 af = *(const bf16x8*)(smem + rowA * 256 + ca);
            bf16x8 bf = *(const bf16x8*)(smem + 16384 + rowB * 256 + cb);
            acc = __builtin_amdgcn_mfma_f32_32x32x16_bf16(af, bf, acc, 0, 0, 0);
        }
        // epilogue: o = max(sq_i + sq_j - 2*dot, EPS)
        float sqj = sqB[rowB];
        float o2 = 0.f, colv = 0.f;
        #pragma unroll
        for (int m = 0; m < 16; m++) {
            int row = (m & 3) + 8 * (m >> 2) + 4 * kh;   // C layout (verified m74/m101)
            float o = fmaxf(sqA[rh * 32 + row] + sqj - 2.0f * acc[m], EPSF);
            o2 = fmaf(o, o, o2);
            colv += o;
        }
        atomicAdd(&cols[qc * 32 + (l & 31)], colv);
        o2 = waveReduce(o2);
        if (l == 0) osum[w] = o2;
        __syncthreads();
        if (t < 64) atomicAdd(&ws[CSO + j0 + t], cols[t]);
        if (t == 0) atomicAdd(&ws[SC + 4], osum[0] + osum[1] + osum[2] + osum[3]);
    } else {
        // ---- box pairwise ----
        float* sCl = (float*)smem;           // 16 rows * 16 f
        float* sCh = (float*)(smem + 1024);
        float* p1  = (float*)(smem + 2048);
        float* p2  = (float*)(smem + 2064);
        int b2 = b - 1024;
        int ic = b2 >> 3, jt = b2 & 7;
        int j = jt * 256 + t;

        float4 clv[4], chv[4];
        #pragma unroll
        for (int qq = 0; qq < 4; qq++) {
            clv[qq] = ((const float4*)(ws + CLG + j * DD))[qq];
            chv[qq] = ((const float4*)(ws + CHG + j * DD))[qq];
        }
        if (t < 64) ((float4*)sCl)[t] = ((const float4*)(ws + CLG + ic * 16 * DD))[t];
        else if (t < 128) ((float4*)sCh)[t - 64] = ((const float4*)(ws + CHG + ic * 16 * DD))[t - 64];
        __syncthreads();

        float colAcc = 0.f, ovAcc = 0.f, r2Acc = 0.f;
        #pragma unroll 4
        for (int ii = 0; ii < 16; ii++) {
            float rr = 0.f, ov = 0.f;
            #pragma unroll
            for (int qq = 0; qq < 4; qq++) {
                float4 ci = ((const float4*)(sCl + ii * DD))[qq];
                float4 hi = ((const float4*)(sCh + ii * DD))[qq];
                float4 cj = clv[qq], hj = chv[qq];
                rr += fabsf(cj.x - ci.x) + fabsf(cj.y - ci.y)
                    + fabsf(cj.z - ci.z) + fabsf(cj.w - ci.w);
                ov += fmaxf(fminf(hj.x, hi.x) - fmaxf(cj.x, ci.x), 0.f)
                    + fmaxf(fminf(hj.y, hi.y) - fmaxf(cj.y, ci.y), 0.f)
                    + fmaxf(fminf(hj.z, hi.z) - fmaxf(cj.z, ci.z), 0.f)
                    + fmaxf(fminf(hj.w, hi.w) - fmaxf(cj.w, ci.w), 0.f);
            }
            if (ic * 16 + ii != j) ovAcc += ov;
            colAcc += rr;
            r2Acc = fmaf(rr, rr, r2Acc);
        }
        atomicAdd(&ws[CSR + j], colAcc);
        float ovW = waveReduce(ovAcc), r2W = waveReduce(r2Acc);
        if ((t & 63) == 0) { p1[t >> 6] = ovW; p2[t >> 6] = r2W; }
        __syncthreads();
        if (t == 0) {
            atomicAdd(&ws[SC + 2], p1[0] + p1[1] + p1[2] + p1[3]);
            atomicAdd(&ws[SC + 3], p2[0] + p2[1] + p2[2] + p2[3]);
        }
    }
}

// ---------------- kernel C: finalize ----------------
__global__ __launch_bounds__(256) void k_final(
    const float* __restrict__ pR, float* __restrict__ ws, float* __restrict__ out)
{
    int t = threadIdx.x;
    __shared__ float scol[16], red[16];
    float sum_r2 = ws[SC + 3], sum_o2 = ws[SC + 4];
    float nr = fmaxf(sqrtf(sum_r2), EPSF);
    float no = fmaxf(sqrtf(sum_o2), EPSF);

    float s_dn2 = 0.f, s_cross = 0.f;
    for (int j = t; j < NN; j += 256) {
        float dn = ws[CSR + j] / nr;
        s_dn2 = fmaf(dn, dn, s_dn2);
        s_cross = fmaf(dn, ws[CSO + j], s_cross);
    }
    float ex = 0.f, sh = 0.f;
    if (t < 128) { ex = ws[PEX + t]; sh = ws[PSH + t]; }

    if (t < 16) scol[t] = 0.f;
    __syncthreads();
    {
        int d = t & 15, gq = t >> 4;
        float cs = 0.f;
        for (int m = gq; m < 128; m += 16) cs += ws[PCSD + m * 16 + d];
        atomicAdd(&scol[d], cs);
    }
    float a = waveReduce(s_dn2), c = waveReduce(s_cross);
    float e = waveReduce(ex),  s = waveReduce(sh);
    if ((t & 63) == 0) {
        int w = t >> 6;
        red[w] = a; red[4 + w] = c; red[8 + w] = e; red[12 + w] = s;
    }
    __syncthreads();
    if (t == 0) {
        float dn2   = red[0] + red[1] + red[2] + red[3];
        float cross = red[4] + red[5] + red[6] + red[7];
        float lossExceed = red[8] + red[9] + red[10] + red[11];
        float lossShape  = red[12] + red[13] + red[14] + red[15];
        float ld2 = sum_o2 / (no * no) - (2.0f / no) * cross + (float)NN * dn2;
        float lossDistance = sqrtf(fmaxf(ld2, 0.f));
        float lossPositive = 0.f;
        #pragma unroll
        for (int d = 0; d < 16; d++)
            lossPositive += fmaxf(pR[d] - scol[d], 0.f);
        out[0] = lossDistance + lossShape + lossExceed + ws[SC + 2] + lossPositive;
    }
}

extern "C" void kernel_launch(void* const* d_in, const int* in_sizes, int n_in,
                              void* d_out, int out_size, void* d_ws, size_t ws_size,
                              hipStream_t stream) {
    const int*   idx   = (const int*)d_in[0];
    const float* omega = (const float*)d_in[1];
    // d_in[2] = epoch (unused)
    const float* chL   = (const float*)d_in[3];
    const float* chH   = (const float*)d_in[4];
    const float* pL    = (const float*)d_in[5];
    const float* pH    = (const float*)d_in[6];
    const float* pR    = (const float*)d_in[7];
    const float* lr    = (const float*)d_in[8];
    float* ws  = (float*)d_ws;
    float* out = (float*)d_out;

    k_setup<<<dim3(128), 256, 0, stream>>>(idx, omega, chL, chH, pL, pH, pR, lr, ws);
    k_pair<<<dim3(2048), 256, 0, stream>>>(omega, ws);
    k_final<<<1, 256, 0, stream>>>(pR, ws, out);
}

// Round 4
// 58.729 us; speedup vs baseline: 1.8699x; 1.0463x over previous
//
#include <hip/hip_runtime.h>
#include <math.h>

#define NN 2048
#define DD 16
#define HH 128
#define EPSF 1e-10f
#define PIO2 1.57079632679489662f

// ---------------- workspace float layout ----------------
#define SC    0      // 8 scalars: [2]=lossOverlap, [3]=sum_r2, [4]=sum_o2
#define PEX   8      // 128 per-block partial lossExceed
#define PSH   136    // 128 per-block partial lossShapeLike
#define PCSD  264    // 128*16 per-block partial colsumDiff
#define CSR   2312   // colsum_r[2048]
#define CSO   4360   // colsum_o[2048]
#define SQ    6408   // sq[2048]
#define CLG   8456   // gathered lower [N*16]
#define CHG   (CLG + NN*DD)          // 41224
#define OMB   (CHG + NN*DD)          // 73992: omega bf16 copy (2048*128 bf16)
#define OMB_B (OMB * 4)              // byte offset, 16B aligned

typedef __attribute__((ext_vector_type(8)))  short  bf16x8;
typedef __attribute__((ext_vector_type(16))) float  f32x16;

__device__ __forceinline__ float waveReduce(float v) {
    #pragma unroll
    for (int o = 32; o > 0; o >>= 1) v += __shfl_down(v, o, 64);
    return v;
}

__device__ __forceinline__ unsigned int bf16rne(float x) {
    unsigned int u = __float_as_uint(x);
    u += 0x7fff + ((u >> 16) & 1);
    return u >> 16;
}
__device__ __forceinline__ unsigned int pkbf(float a, float b) {
    return bf16rne(a) | (bf16rne(b) << 16);
}

// ---------------- kernel A: gather + elementwise + sq + bf16 convert + zeroing ----
// one (row, dim) per thread: 128 blocks x 256
__global__ __launch_bounds__(256) void k_setup(
    const int* __restrict__ idx, const float* __restrict__ omega,
    const float* __restrict__ chL, const float* __restrict__ chH,
    const float* __restrict__ pL, const float* __restrict__ pH,
    const float* __restrict__ pR, const float* __restrict__ lr,
    float* __restrict__ ws)
{
    int t = threadIdx.x, b = blockIdx.x;
    int g = b * 256 + t;
    int i = g >> 4, d = g & 15;
    int id = idx[i];

    float c0 = chL[id * DD + d];
    float c1 = chH[id * DD + d];
    ws[CLG + i * DD + d] = c0;
    ws[CHG + i * DD + d] = c1;

    // zero accumulators for k_pair (stream-ordered before it)
    if (t < 16) { ws[CSR + b * 16 + t] = 0.f; ws[CSO + b * 16 + t] = 0.f; }
    if (b == 0 && t >= 16 && t < 24) ws[SC + (t - 16)] = 0.f;

    float l = pL[d], h = pH[d], r = pR[d];
    float ex = fmaxf(l - c0, 0.f) + fmaxf(c1 - h, 0.f)
             + fmaxf(l - c1, 0.f) + fmaxf(c0 - h, 0.f);
    float diff = c1 - c0;
    float denom = lr[id];
    float numer = fmaxf(diff / r, EPSF);
    float sdiv = fminf(fmaxf(numer / denom, 0.01f), 1.99f);
    float sh = fabsf(tanf((sdiv - 1.0f) * PIO2));

    // sq_i: lane d covers omega[i*128 + d*8 .. +8); also emit bf16 copy
    const float4* op = (const float4*)(omega + i * HH + d * 8);
    float4 v0 = op[0], v1 = op[1];
    float s = v0.x*v0.x + v0.y*v0.y + v0.z*v0.z + v0.w*v0.w
            + v1.x*v1.x + v1.y*v1.y + v1.z*v1.z + v1.w*v1.w;
    *(uint4*)((char*)ws + OMB_B + i * 256 + d * 16) =
        make_uint4(pkbf(v0.x, v0.y), pkbf(v0.z, v0.w), pkbf(v1.x, v1.y), pkbf(v1.z, v1.w));
    s += __shfl_xor(s, 1, 64);
    s += __shfl_xor(s, 2, 64);
    s += __shfl_xor(s, 4, 64);
    s += __shfl_xor(s, 8, 64);
    if (d == 0) ws[SQ + i] = s;

    float dsw = diff;
    dsw += __shfl_xor(dsw, 16, 64);
    dsw += __shfl_xor(dsw, 32, 64);

    __shared__ float scol[16], pex[4], psh[4];
    if (t < 16) scol[t] = 0.f;
    __syncthreads();
    if ((t & 63) < 16) atomicAdd(&scol[t & 15], dsw);
    float exw = waveReduce(ex), shw = waveReduce(sh);
    if ((t & 63) == 0) { pex[t >> 6] = exw; psh[t >> 6] = shw; }
    __syncthreads();
    if (t < 16) ws[PCSD + b * 16 + t] = scol[t];
    if (t == 0) {
        ws[PEX + b] = pex[0] + pex[1] + pex[2] + pex[3];
        ws[PSH + b] = psh[0] + psh[1] + psh[2] + psh[3];
    }
}

// ---------------- fused pairwise kernel ----------------
// blocks [0,528): omega Gram, upper-triangle 64x64 tiles (bf16 MFMA)
// blocks [528,1552): box pairwise, register-tiled, no LDS
__global__ __launch_bounds__(256) void k_pair(float* __restrict__ ws)
{
    __shared__ __align__(16) char smem[33840];
    int t = threadIdx.x;
    int b = blockIdx.x;

    if (b < 528) {
        // ---- Gram tile (ci <= cj) ----
        int rem = b, ci = 0;
        while (rem >= 32 - ci) { rem -= 32 - ci; ci++; }
        int cj = ci + rem;
        int i0 = ci * 64, j0 = cj * 64;
        bool offd = (ci != cj);
        const char* wsb = (const char*)ws;

        // stage A (and B if off-diagonal): bf16, XOR-swizzled positions
        #pragma unroll
        for (int k = 0; k < 4; k++) {
            int s = t + k * 256;
            int r = s >> 4, c = s & 15;
            int sc = (c ^ (r & 7)) * 16;
            *(uint4*)(smem + r * 256 + c * 16) =
                *(const uint4*)(wsb + OMB_B + (i0 + r) * 256 + sc);
            if (offd)
                *(uint4*)(smem + 16384 + r * 256 + c * 16) =
                    *(const uint4*)(wsb + OMB_B + (j0 + r) * 256 + sc);
        }
        float* sqA  = (float*)(smem + 32768);
        float* sqB  = (float*)(smem + 33024);
        float* cols = (float*)(smem + 33280);
        float* rows = (float*)(smem + 33536);
        float* osum = (float*)(smem + 33792);
        if (t < 64) sqA[t] = ws[SQ + i0 + t];
        else if (t < 128) sqB[t - 64] = ws[SQ + j0 + (t - 64)];
        else if (t < 192) cols[t - 128] = 0.f;
        else rows[t - 192] = 0.f;
        __syncthreads();

        const char* smA = smem;
        const char* smB = offd ? (smem + 16384) : smem;
        int w = t >> 6, l = t & 63;
        int rh = w >> 1, qc = w & 1, kh = l >> 5;
        int rowA = rh * 32 + (l & 31);
        int rowB = qc * 32 + (l & 31);
        f32x16 acc;
        #pragma unroll
        for (int m = 0; m < 16; m++) acc[m] = 0.f;
        #pragma unroll
        for (int s = 0; s < 8; s++) {
            int ca = ((2 * s + kh) ^ (rowA & 7)) * 16;
            int cb = ((2 * s + kh) ^ (rowB & 7)) * 16;
            bf16x8 af = *(const bf16x8*)(smA + rowA * 256 + ca);
            bf16x8 bf = *(const bf16x8*)(smB + rowB * 256 + cb);
            acc = __builtin_amdgcn_mfma_f32_32x32x16_bf16(af, bf, acc, 0, 0, 0);
        }
        // epilogue: o = max(sq_i + sq_j - 2*dot, EPS); col sums + (offd) row sums
        float sqj = sqB[rowB];
        float o2 = 0.f, colv = 0.f;
        #pragma unroll
        for (int m = 0; m < 16; m++) {
            int row = (m & 3) + 8 * (m >> 2) + 4 * kh;   // validated C layout
            float o = fmaxf(sqA[rh * 32 + row] + sqj - 2.0f * acc[m], EPSF);
            o2 = fmaf(o, o, o2);
            colv += o;
            if (offd) {
                float rs = o;
                rs += __shfl_xor(rs, 1, 64);
                rs += __shfl_xor(rs, 2, 64);
                rs += __shfl_xor(rs, 4, 64);
                rs += __shfl_xor(rs, 8, 64);
                rs += __shfl_xor(rs, 16, 64);
                if ((l & 31) == 0) atomicAdd(&rows[rh * 32 + row], rs);
            }
        }
        atomicAdd(&cols[qc * 32 + (l & 31)], colv);
        o2 = waveReduce(o2);
        if (l == 0) osum[w] = o2;
        __syncthreads();
        if (t < 64) {
            atomicAdd(&ws[CSO + j0 + t], cols[t]);
            if (offd) atomicAdd(&ws[CSO + i0 + t], rows[t]);
        }
        if (t == 0) {
            float o2s = osum[0] + osum[1] + osum[2] + osum[3];
            atomicAdd(&ws[SC + 4], offd ? 2.0f * o2s : o2s);
        }
    } else {
        // ---- box pairwise: 2 j/thread in regs, 8 uniform i-rows, no LDS ----
        int b2 = b - 528;
        int jg = b2 & 3, ic = b2 >> 2;
        int j0 = jg * 512 + t * 2;
        const float* clg = ws + CLG;
        const float* chg = ws + CHG;

        float4 lj0[4], hj0[4], lj1[4], hj1[4];
        #pragma unroll
        for (int q = 0; q < 4; q++) {
            lj0[q] = ((const float4*)(clg + j0 * DD))[q];
            hj0[q] = ((const float4*)(chg + j0 * DD))[q];
            lj1[q] = ((const float4*)(clg + (j0 + 1) * DD))[q];
            hj1[q] = ((const float4*)(chg + (j0 + 1) * DD))[q];
        }
        float racc0 = 0.f, racc1 = 0.f, r2 = 0.f, ov = 0.f;
        #pragma unroll
        for (int ii = 0; ii < 8; ii++) {
            int i = ic * 8 + ii;
            float r0 = 0.f, o0 = 0.f, r1 = 0.f, o1 = 0.f;
            #pragma unroll
            for (int q = 0; q < 4; q++) {
                float4 li = ((const float4*)(clg + i * DD))[q];
                float4 hi = ((const float4*)(chg + i * DD))[q];
                r0 += fabsf(lj0[q].x - li.x) + fabsf(lj0[q].y - li.y)
                    + fabsf(lj0[q].z - li.z) + fabsf(lj0[q].w - li.w);
                o0 += fmaxf(fminf(hj0[q].x, hi.x) - fmaxf(lj0[q].x, li.x), 0.f)
                    + fmaxf(fminf(hj0[q].y, hi.y) - fmaxf(lj0[q].y, li.y), 0.f)
                    + fmaxf(fminf(hj0[q].z, hi.z) - fmaxf(lj0[q].z, li.z), 0.f)
                    + fmaxf(fminf(hj0[q].w, hi.w) - fmaxf(lj0[q].w, li.w), 0.f);
                r1 += fabsf(lj1[q].x - li.x) + fabsf(lj1[q].y - li.y)
                    + fabsf(lj1[q].z - li.z) + fabsf(lj1[q].w - li.w);
                o1 += fmaxf(fminf(hj1[q].x, hi.x) - fmaxf(lj1[q].x, li.x), 0.f)
                    + fmaxf(fminf(hj1[q].y, hi.y) - fmaxf(lj1[q].y, li.y), 0.f)
                    + fmaxf(fminf(hj1[q].z, hi.z) - fmaxf(lj1[q].z, li.z), 0.f)
                    + fmaxf(fminf(hj1[q].w, hi.w) - fmaxf(lj1[q].w, li.w), 0.f);
            }
            if (i != j0)     ov += o0;
            if (i != j0 + 1) ov += o1;
            racc0 += r0;
            racc1 += r1;
            r2 = fmaf(r0, r0, fmaf(r1, r1, r2));
        }
        atomicAdd(&ws[CSR + j0], racc0);
        atomicAdd(&ws[CSR + j0 + 1], racc1);
        float* boxp = (float*)(smem + 33808);
        float ovW = waveReduce(ov), r2W = waveReduce(r2);
        int l = t & 63, w = t >> 6;
        if (l == 0) { boxp[w] = ovW; boxp[4 + w] = r2W; }
        __syncthreads();
        if (t == 0) {
            atomicAdd(&ws[SC + 2], boxp[0] + boxp[1] + boxp[2] + boxp[3]);
            atomicAdd(&ws[SC + 3], boxp[4] + boxp[5] + boxp[6] + boxp[7]);
        }
    }
}

// ---------------- kernel C: finalize ----------------
__global__ __launch_bounds__(256) void k_final(
    const float* __restrict__ pR, float* __restrict__ ws, float* __restrict__ out)
{
    int t = threadIdx.x;
    __shared__ float scol[16], red[16];
    float sum_r2 = ws[SC + 3], sum_o2 = ws[SC + 4];
    float nr = fmaxf(sqrtf(sum_r2), EPSF);
    float no = fmaxf(sqrtf(sum_o2), EPSF);

    float s_dn2 = 0.f, s_cross = 0.f;
    for (int j = t; j < NN; j += 256) {
        float dn = ws[CSR + j] / nr;
        s_dn2 = fmaf(dn, dn, s_dn2);
        s_cross = fmaf(dn, ws[CSO + j], s_cross);
    }
    float ex = 0.f, sh = 0.f;
    if (t < 128) { ex = ws[PEX + t]; sh = ws[PSH + t]; }

    if (t < 16) scol[t] = 0.f;
    __syncthreads();
    {
        int d = t & 15, gq = t >> 4;
        float cs = 0.f;
        for (int m = gq; m < 128; m += 16) cs += ws[PCSD + m * 16 + d];
        atomicAdd(&scol[d], cs);
    }
    float a = waveReduce(s_dn2), c = waveReduce(s_cross);
    float e = waveReduce(ex),  s = waveReduce(sh);
    if ((t & 63) == 0) {
        int w = t >> 6;
        red[w] = a; red[4 + w] = c; red[8 + w] = e; red[12 + w] = s;
    }
    __syncthreads();
    if (t == 0) {
        float dn2   = red[0] + red[1] + red[2] + red[3];
        float cross = red[4] + red[5] + red[6] + red[7];
        float lossExceed = red[8] + red[9] + red[10] + red[11];
        float lossShape  = red[12] + red[13] + red[14] + red[15];
        float ld2 = sum_o2 / (no * no) - (2.0f / no) * cross + (float)NN * dn2;
        float lossDistance = sqrtf(fmaxf(ld2, 0.f));
        float lossPositive = 0.f;
        #pragma unroll
        for (int d = 0; d < 16; d++)
            lossPositive += fmaxf(pR[d] - scol[d], 0.f);
        out[0] = lossDistance + lossShape + lossExceed + ws[SC + 2] + lossPositive;
    }
}

extern "C" void kernel_launch(void* const* d_in, const int* in_sizes, int n_in,
                              void* d_out, int out_size, void* d_ws, size_t ws_size,
                              hipStream_t stream) {
    const int*   idx   = (const int*)d_in[0];
    const float* omega = (const float*)d_in[1];
    // d_in[2] = epoch (unused)
    const float* chL   = (const float*)d_in[3];
    const float* chH   = (const float*)d_in[4];
    const float* pL    = (const float*)d_in[5];
    const float* pH    = (const float*)d_in[6];
    const float* pR    = (const float*)d_in[7];
    const float* lr    = (const float*)d_in[8];
    float* ws  = (float*)d_ws;
    float* out = (float*)d_out;

    k_setup<<<dim3(128), 256, 0, stream>>>(idx, omega, chL, chH, pL, pH, pR, lr, ws);
    k_pair<<<dim3(528 + 1024), 256, 0, stream>>>(ws);
    k_final<<<1, 256, 0, stream>>>(pR, ws, out);
}

// Round 5
// 50.741 us; speedup vs baseline: 2.1643x; 1.1574x over previous
//
#include <hip/hip_runtime.h>
#include <math.h>

#define NN 2048
#define DD 16
#define HH 128
#define EPSF 1e-10f
#define PIO2 1.57079632679489662f

// ---------------- workspace float layout ----------------
#define SC    0      // 8 scalars: [2]=lossOverlap, [3]=sum_r2, [4]=sum_o2
#define PEX   8      // 128 per-block partial lossExceed
#define PSH   136    // 128 per-block partial lossShapeLike
#define PCSD  264    // 128*16 per-block partial colsumDiff
#define CSR   2312   // colsum_r[2048]
#define CSO   4360   // colsum_o[2048]
#define SQ    6408   // sq[2048]
#define CLG   8456   // gathered lower [N*16]
#define CHG   (CLG + NN*DD)          // 41224
#define OMB   (CHG + NN*DD)          // 73992: omega bf16 copy (2048*128 bf16)
#define OMB_B (OMB * 4)              // byte offset, 16B aligned

typedef __attribute__((ext_vector_type(8)))  short  bf16x8;
typedef __attribute__((ext_vector_type(16))) float  f32x16;

__device__ __forceinline__ float waveReduce(float v) {
    #pragma unroll
    for (int o = 32; o > 0; o >>= 1) v += __shfl_down(v, o, 64);
    return v;
}

__device__ __forceinline__ unsigned int bf16rne(float x) {
    unsigned int u = __float_as_uint(x);
    u += 0x7fff + ((u >> 16) & 1);
    return u >> 16;
}
__device__ __forceinline__ unsigned int pkbf(float a, float b) {
    return bf16rne(a) | (bf16rne(b) << 16);
}

// ---------------- kernel A: gather + elementwise + sq + bf16 convert + zeroing ----
__global__ __launch_bounds__(256) void k_setup(
    const int* __restrict__ idx, const float* __restrict__ omega,
    const float* __restrict__ chL, const float* __restrict__ chH,
    const float* __restrict__ pL, const float* __restrict__ pH,
    const float* __restrict__ pR, const float* __restrict__ lr,
    float* __restrict__ ws)
{
    int t = threadIdx.x, b = blockIdx.x;
    int g = b * 256 + t;
    int i = g >> 4, d = g & 15;
    int id = idx[i];

    float c0 = chL[id * DD + d];
    float c1 = chH[id * DD + d];
    ws[CLG + i * DD + d] = c0;
    ws[CHG + i * DD + d] = c1;

    if (t < 16) { ws[CSR + b * 16 + t] = 0.f; ws[CSO + b * 16 + t] = 0.f; }
    if (b == 0 && t >= 16 && t < 24) ws[SC + (t - 16)] = 0.f;

    float l = pL[d], h = pH[d], r = pR[d];
    float ex = fmaxf(l - c0, 0.f) + fmaxf(c1 - h, 0.f)
             + fmaxf(l - c1, 0.f) + fmaxf(c0 - h, 0.f);
    float diff = c1 - c0;
    float denom = lr[id];
    float numer = fmaxf(diff / r, EPSF);
    float sdiv = fminf(fmaxf(numer / denom, 0.01f), 1.99f);
    float sh = fabsf(tanf((sdiv - 1.0f) * PIO2));

    const float4* op = (const float4*)(omega + i * HH + d * 8);
    float4 v0 = op[0], v1 = op[1];
    float s = v0.x*v0.x + v0.y*v0.y + v0.z*v0.z + v0.w*v0.w
            + v1.x*v1.x + v1.y*v1.y + v1.z*v1.z + v1.w*v1.w;
    *(uint4*)((char*)ws + OMB_B + i * 256 + d * 16) =
        make_uint4(pkbf(v0.x, v0.y), pkbf(v0.z, v0.w), pkbf(v1.x, v1.y), pkbf(v1.z, v1.w));
    s += __shfl_xor(s, 1, 64);
    s += __shfl_xor(s, 2, 64);
    s += __shfl_xor(s, 4, 64);
    s += __shfl_xor(s, 8, 64);
    if (d == 0) ws[SQ + i] = s;

    float dsw = diff;
    dsw += __shfl_xor(dsw, 16, 64);
    dsw += __shfl_xor(dsw, 32, 64);

    __shared__ float scol[16], pex[4], psh[4];
    if (t < 16) scol[t] = 0.f;
    __syncthreads();
    if ((t & 63) < 16) atomicAdd(&scol[t & 15], dsw);
    float exw = waveReduce(ex), shw = waveReduce(sh);
    if ((t & 63) == 0) { pex[t >> 6] = exw; psh[t >> 6] = shw; }
    __syncthreads();
    if (t < 16) ws[PCSD + b * 16 + t] = scol[t];
    if (t == 0) {
        ws[PEX + b] = pex[0] + pex[1] + pex[2] + pex[3];
        ws[PSH + b] = psh[0] + psh[1] + psh[2] + psh[3];
    }
}

// ---------------- fused pairwise kernel ----------------
// blocks [0,1024): omega Gram, full 64x64 tiles (bf16 MFMA), col-sums only
// blocks [1024,1536): box pairwise, 64-i x 128-j tiles, LDS-broadcast i
__global__ __launch_bounds__(256) void k_pair(float* __restrict__ ws)
{
    __shared__ __align__(16) char smem[33552];
    int t = threadIdx.x;
    int b = blockIdx.x;

    if (b < 1024) {
        // ---- Gram tile ----
        int i0 = (b >> 5) * 64, j0 = (b & 31) * 64;
        const char* wsb = (const char*)ws;

        #pragma unroll
        for (int k = 0; k < 4; k++) {
            int s = t + k * 256;
            int r = s >> 4, c = s & 15;
            int sc = (c ^ (r & 7)) * 16;
            *(uint4*)(smem + r * 256 + c * 16) =
                *(const uint4*)(wsb + OMB_B + (i0 + r) * 256 + sc);
            *(uint4*)(smem + 16384 + r * 256 + c * 16) =
                *(const uint4*)(wsb + OMB_B + (j0 + r) * 256 + sc);
        }
        float* sqA  = (float*)(smem + 32768);
        float* sqB  = (float*)(smem + 33024);
        float* cols = (float*)(smem + 33280);
        float* osum = (float*)(smem + 33536);
        if (t < 64) sqA[t] = ws[SQ + i0 + t];
        else if (t < 128) sqB[t - 64] = ws[SQ + j0 + (t - 64)];
        else if (t < 192) cols[t - 128] = 0.f;
        __syncthreads();

        int w = t >> 6, l = t & 63;
        int rh = w >> 1, qc = w & 1, kh = l >> 5;
        int rowA = rh * 32 + (l & 31);
        int rowB = qc * 32 + (l & 31);
        f32x16 acc;
        #pragma unroll
        for (int m = 0; m < 16; m++) acc[m] = 0.f;
        #pragma unroll
        for (int s = 0; s < 8; s++) {
            int ca = ((2 * s + kh) ^ (rowA & 7)) * 16;
            int cb = ((2 * s + kh) ^ (rowB & 7)) * 16;
            bf16x8 af = *(const bf16x8*)(smem + rowA * 256 + ca);
            bf16x8 bf = *(const bf16x8*)(smem + 16384 + rowB * 256 + cb);
            acc = __builtin_amdgcn_mfma_f32_32x32x16_bf16(af, bf, acc, 0, 0, 0);
        }
        float sqj = sqB[rowB];
        float o2 = 0.f, colv = 0.f;
        #pragma unroll
        for (int m = 0; m < 16; m++) {
            int row = (m & 3) + 8 * (m >> 2) + 4 * kh;   // validated C layout
            float o = fmaxf(sqA[rh * 32 + row] + sqj - 2.0f * acc[m], EPSF);
            o2 = fmaf(o, o, o2);
            colv += o;
        }
        atomicAdd(&cols[qc * 32 + (l & 31)], colv);
        o2 = waveReduce(o2);
        if (l == 0) osum[w] = o2;
        __syncthreads();
        if (t < 64) atomicAdd(&ws[CSO + j0 + t], cols[t]);
        if (t == 0) atomicAdd(&ws[SC + 4], osum[0] + osum[1] + osum[2] + osum[3]);
    } else {
        // ---- box pairwise ----
        float* sCl  = (float*)smem;            // 64*16 f = 4KB
        float* sCh  = (float*)(smem + 4096);   // 4KB
        float* scol = (float*)(smem + 8192);   // 128 f
        float* boxp = (float*)(smem + 8704);   // 8 f
        int b2 = b - 1024;
        int it = b2 >> 4;      // 32 i-tiles of 64
        int jt = b2 & 15;      // 16 j-tiles of 128

        // stage i-tile (coalesced) + zero scol
        ((float4*)sCl)[t] = ((const float4*)(ws + CLG + it * 64 * DD))[t];
        ((float4*)sCh)[t] = ((const float4*)(ws + CHG + it * 64 * DD))[t];
        if (t < 128) scol[t] = 0.f;

        // 2 j-rows per thread in registers
        int jl = t & 63;
        int j0 = jt * 128 + jl, j1 = j0 + 64;
        float4 l0[4], h0[4], l1[4], h1[4];
        #pragma unroll
        for (int q = 0; q < 4; q++) {
            l0[q] = ((const float4*)(ws + CLG + j0 * DD))[q];
            h0[q] = ((const float4*)(ws + CHG + j0 * DD))[q];
            l1[q] = ((const float4*)(ws + CLG + j1 * DD))[q];
            h1[q] = ((const float4*)(ws + CHG + j1 * DD))[q];
        }
        __syncthreads();

        int isub = t >> 6;   // wave-uniform i-subset
        float ca0 = 0.f, ca1 = 0.f, ov = 0.f, r2 = 0.f;
        #pragma unroll 4
        for (int ii = 0; ii < 16; ii++) {
            int il = isub * 16 + ii;
            int ig = it * 64 + il;
            float r0 = 0.f, o0 = 0.f, r1 = 0.f, o1 = 0.f;
            #pragma unroll
            for (int q = 0; q < 4; q++) {
                float4 li = ((const float4*)(sCl + il * DD))[q];   // broadcast
                float4 hi = ((const float4*)(sCh + il * DD))[q];
                r0 += fabsf(l0[q].x - li.x) + fabsf(l0[q].y - li.y)
                    + fabsf(l0[q].z - li.z) + fabsf(l0[q].w - li.w);
                o0 += fmaxf(fminf(h0[q].x, hi.x) - fmaxf(l0[q].x, li.x), 0.f)
                    + fmaxf(fminf(h0[q].y, hi.y) - fmaxf(l0[q].y, li.y), 0.f)
                    + fmaxf(fminf(h0[q].z, hi.z) - fmaxf(l0[q].z, li.z), 0.f)
                    + fmaxf(fminf(h0[q].w, hi.w) - fmaxf(l0[q].w, li.w), 0.f);
                r1 += fabsf(l1[q].x - li.x) + fabsf(l1[q].y - li.y)
                    + fabsf(l1[q].z - li.z) + fabsf(l1[q].w - li.w);
                o1 += fmaxf(fminf(h1[q].x, hi.x) - fmaxf(l1[q].x, li.x), 0.f)
                    + fmaxf(fminf(h1[q].y, hi.y) - fmaxf(l1[q].y, li.y), 0.f)
                    + fmaxf(fminf(h1[q].z, hi.z) - fmaxf(l1[q].z, li.z), 0.f)
                    + fmaxf(fminf(h1[q].w, hi.w) - fmaxf(l1[q].w, li.w), 0.f);
            }
            if (ig != j0) ov += o0;
            if (ig != j1) ov += o1;
            ca0 += r0;
            ca1 += r1;
            r2 = fmaf(r0, r0, fmaf(r1, r1, r2));
        }
        atomicAdd(&scol[jl], ca0);
        atomicAdd(&scol[jl + 64], ca1);
        float ovW = waveReduce(ov), r2W = waveReduce(r2);
        int w = t >> 6;
        if ((t & 63) == 0) { boxp[w] = ovW; boxp[4 + w] = r2W; }
        __syncthreads();
        if (t < 128) atomicAdd(&ws[CSR + jt * 128 + t], scol[t]);
        if (t == 0) {
            atomicAdd(&ws[SC + 2], boxp[0] + boxp[1] + boxp[2] + boxp[3]);
            atomicAdd(&ws[SC + 3], boxp[4] + boxp[5] + boxp[6] + boxp[7]);
        }
    }
}

// ---------------- kernel C: finalize ----------------
__global__ __launch_bounds__(256) void k_final(
    const float* __restrict__ pR, float* __restrict__ ws, float* __restrict__ out)
{
    int t = threadIdx.x;
    __shared__ float scol[16], red[16];
    float sum_r2 = ws[SC + 3], sum_o2 = ws[SC + 4];
    float nr = fmaxf(sqrtf(sum_r2), EPSF);
    float no = fmaxf(sqrtf(sum_o2), EPSF);

    float s_dn2 = 0.f, s_cross = 0.f;
    for (int j = t; j < NN; j += 256) {
        float dn = ws[CSR + j] / nr;
        s_dn2 = fmaf(dn, dn, s_dn2);
        s_cross = fmaf(dn, ws[CSO + j], s_cross);
    }
    float ex = 0.f, sh = 0.f;
    if (t < 128) { ex = ws[PEX + t]; sh = ws[PSH + t]; }

    if (t < 16) scol[t] = 0.f;
    __syncthreads();
    {
        int d = t & 15, gq = t >> 4;
        float cs = 0.f;
        for (int m = gq; m < 128; m += 16) cs += ws[PCSD + m * 16 + d];
        atomicAdd(&scol[d], cs);
    }
    float a = waveReduce(s_dn2), c = waveReduce(s_cross);
    float e = waveReduce(ex),  s = waveReduce(sh);
    if ((t & 63) == 0) {
        int w = t >> 6;
        red[w] = a; red[4 + w] = c; red[8 + w] = e; red[12 + w] = s;
    }
    __syncthreads();
    if (t == 0) {
        float dn2   = red[0] + red[1] + red[2] + red[3];
        float cross = red[4] + red[5] + red[6] + red[7];
        float lossExceed = red[8] + red[9] + red[10] + red[11];
        float lossShape  = red[12] + red[13] + red[14] + red[15];
        float ld2 = sum_o2 / (no * no) - (2.0f / no) * cross + (float)NN * dn2;
        float lossDistance = sqrtf(fmaxf(ld2, 0.f));
        float lossPositive = 0.f;
        #pragma unroll
        for (int d = 0; d < 16; d++)
            lossPositive += fmaxf(pR[d] - scol[d], 0.f);
        out[0] = lossDistance + lossShape + lossExceed + ws[SC + 2] + lossPositive;
    }
}

extern "C" void kernel_launch(void* const* d_in, const int* in_sizes, int n_in,
                              void* d_out, int out_size, void* d_ws, size_t ws_size,
                              hipStream_t stream) {
    const int*   idx   = (const int*)d_in[0];
    const float* omega = (const float*)d_in[1];
    // d_in[2] = epoch (unused)
    const float* chL   = (const float*)d_in[3];
    const float* chH   = (const float*)d_in[4];
    const float* pL    = (const float*)d_in[5];
    const float* pH    = (const float*)d_in[6];
    const float* pR    = (const float*)d_in[7];
    const float* lr    = (const float*)d_in[8];
    float* ws  = (float*)d_ws;
    float* out = (float*)d_out;

    k_setup<<<dim3(128), 256, 0, stream>>>(idx, omega, chL, chH, pL, pH, pR, lr, ws);
    k_pair<<<dim3(1536), 256, 0, stream>>>(ws);
    k_final<<<1, 256, 0, stream>>>(pR, ws, out);
}